// Round 6
// baseline (1264.338 us; speedup 1.0000x reference)
//
#include <hip/hip_runtime.h>

// Sorted-segment product: out[i] = prod_{j: csr[j]==i} x[ptrs[j]], empty -> 0.
//
// R6: R5 (32KB LDS blocks, 85% occ, 3.56 TB/s fabric rate) + soft global
// phase gate to kill cross-block window drift (R5: fills 250->640MB because
// 128 independent blocks/XCD drifted across >4MB of active windows).
// Gate: after window w, each block atomicAdds an arrival counter (in d_ws)
// and lane 0 spins (s_sleep, bounded budget, fail-latch) until all active
// blocks arrive. Correctness-neutral by construction: polls only ever see
// values <= target, so premature release is impossible and timeout only
// costs time. Windows widened to 2MB (nwin=8) -> 16 gates total.

#define EPT       16              // edges per thread (pt[16]+g[16] = 32 VGPRs)
#define EPT_SHIFT 4
#define BLK       512             // threads per block (8 waves)
#define MSC       (BLK * EPT)     // 8192 edges per superchunk -> 32KB LDS
#define NBLK      1024            // persistent blocks (~4 per CU)
#define WSHIFT    19              // window = 2^19 floats = 2 MB
#define MAXGATES  1024            // counters available in d_ws (4KB)
#define SPIN_BUDGET 4000

__global__ __launch_bounds__(BLK, 8) void prodseg_main(
    const float* __restrict__ x,
    const int*   __restrict__ ptrs,
    const int*   __restrict__ csr,
    float*       __restrict__ out,
    unsigned*    gate_cnt,        // MAXGATES counters, pre-zeroed (or null)
    int E, int S, int F /* # full superchunks */, int nwin)
{
    __shared__ float gbuf[MSC];   // column-major: edge (t,k) -> gbuf[k*BLK + t]
    __shared__ unsigned gate_fail;
    const int t = threadIdx.x;
    if (t == 0) gate_fail = (gate_cnt == nullptr) ? 1u : 0u;
    const int ngen = (F + (int)gridDim.x - 1) / (int)gridDim.x;

    for (int gen = 0; gen < ngen; ++gen) {
        int sc = gen * (int)gridDim.x + (int)blockIdx.x;
        if (sc >= F) break;                    // block-uniform exit
        const int sbase = sc * MSC;
        const int gbase = sbase + t * EPT;
        // blocks participating in this generation (gate target)
        int remain = F - gen * (int)gridDim.x;
        unsigned target = (unsigned)((remain < (int)gridDim.x) ? remain
                                                               : (int)gridDim.x);

        // ---- stage my 16 ptrs into registers (vectorized, aligned) ----
        int pt[EPT];
        {
            const int4* p4 = reinterpret_cast<const int4*>(ptrs + gbase);
            #pragma unroll
            for (int i = 0; i < EPT / 4; ++i) {
                int4 v = p4[i];
                pt[4*i+0] = v.x; pt[4*i+1] = v.y;
                pt[4*i+2] = v.z; pt[4*i+3] = v.w;
            }
        }

        // ---- window-phased gather with global phase gate ----
        float g[EPT];
        for (int w = 0; w < nwin; ++w) {
            // 1) predicated loads only — independent, all issue (MLP)
            #pragma unroll
            for (int k = 0; k < EPT; ++k)
                if ((pt[k] >> WSHIFT) == w) g[k] = x[pt[k]];
            // 2) mirror to LDS for cross-thread run walks
            #pragma unroll
            for (int k = 0; k < EPT; ++k)
                if ((pt[k] >> WSHIFT) == w) gbuf[k * BLK + t] = g[k];
            // block-internal alignment; drains loads (arrival => window done)
            __syncthreads();
            // 3) global phase gate (skip once latched as failed)
            int gate_idx = gen * nwin + w;
            if (gate_fail == 0u && gate_idx < MAXGATES && w < nwin - 1) {
                if (t == 0) {
                    unsigned* c = gate_cnt + gate_idx;
                    atomicAdd(c, 1u);          // device-scope arrival
                    int budget = SPIN_BUDGET;
                    unsigned v;
                    do {
                        v = __hip_atomic_load(c, __ATOMIC_RELAXED,
                                              __HIP_MEMORY_SCOPE_AGENT);
                        if (v >= target) break;
                        __builtin_amdgcn_s_sleep(2);
                    } while (--budget);
                    if (v < target) gate_fail = 1u;  // latch: throttle failed
                }
                __syncthreads();               // release block
            }
        }

        // ---- product phase (run ownership, exact) ----
        int prev = (gbase == 0) ? -1 : csr[gbase - 1];
        const int4* c4 = reinterpret_cast<const int4*>(csr + gbase);
        int cur = 0; bool own = false; float prod = 1.0f;
        #pragma unroll
        for (int i = 0; i < EPT / 4; ++i) {
            int4 c = c4[i];
            int sv[4] = {c.x, c.y, c.z, c.w};
            #pragma unroll
            for (int j = 0; j < 4; ++j) {
                const int k = 4 * i + j;
                int sg = sv[j];
                if (k == 0) {
                    cur = sg; own = (sg != prev);
                    prod = own ? g[0] : 1.0f;
                    if (own)
                        for (int q = prev + 1; q < cur; ++q) out[q] = 0.0f;
                } else {
                    if (sg == cur) {
                        prod *= g[k];          // harmless if !own (never stored)
                    } else {
                        if (own) out[cur] = prod;
                        for (int q = cur + 1; q < sg; ++q) out[q] = 0.0f;
                        cur = sg; own = true; prod = g[k];
                    }
                }
            }
        }
        // final run: walk forward; in-superchunk values come from LDS
        if (own) {
            int idx = gbase + EPT;
            while (idx < E) {
                if (csr[idx] != cur) break;
                float v;
                int local = idx - sbase;
                if (local < MSC)
                    v = gbuf[(local & (EPT - 1)) * BLK + (local >> EPT_SHIFT)];
                else
                    v = x[ptrs[idx]];
                prod *= v; ++idx;
            }
            out[cur] = prod;
            if (idx == E)
                for (int q = cur + 1; q < S; ++q) out[q] = 0.0f;
        }
        __syncthreads();   // protect gbuf before next generation
    }
}

// Generic tail (E % MSC != 0) — R1-proven logic; not launched for E = 2^24.
#define TK 8
__global__ __launch_bounds__(256) void prodseg_tail(
    const float* __restrict__ x,
    const int*   __restrict__ ptrs,
    const int*   __restrict__ csr,
    float*       __restrict__ out,
    int E0, int E, int S)
{
    int t = blockIdx.x * blockDim.x + threadIdx.x;
    int base = E0 + t * TK;
    if (base >= E) return;
    int prev = (base == 0) ? -1 : csr[base - 1];
    int n = (base + TK <= E) ? TK : (E - base);

    int cur = 0; bool own = false; float prod = 1.0f;
    for (int k = 0; k < n; ++k) {
        int sg = csr[base + k];
        float gv = x[ptrs[base + k]];
        if (k == 0) {
            cur = sg; own = (sg != prev);
            prod = own ? gv : 1.0f;
            if (own) for (int q = prev + 1; q < cur; ++q) out[q] = 0.0f;
        } else if (sg == cur) {
            prod *= gv;
        } else {
            if (own) out[cur] = prod;
            for (int q = cur + 1; q < sg; ++q) out[q] = 0.0f;
            cur = sg; own = true; prod = gv;
        }
    }
    if (own) {
        int idx = base + n;
        while (idx < E && csr[idx] == cur) { prod *= x[ptrs[idx]]; ++idx; }
        out[cur] = prod;
        if (idx == E) for (int q = cur + 1; q < S; ++q) out[q] = 0.0f;
    }
}

extern "C" void kernel_launch(void* const* d_in, const int* in_sizes, int n_in,
                              void* d_out, int out_size, void* d_ws, size_t ws_size,
                              hipStream_t stream) {
    const float* x    = (const float*)d_in[0];
    const int*   ptrs = (const int*)d_in[1];
    const int*   csr  = (const int*)d_in[2];
    float*       out  = (float*)d_out;
    int N = in_sizes[0];
    int E = in_sizes[1];
    int S = out_size;

    int F  = E / MSC;                                   // full superchunks
    int E0 = F * MSC;
    int nwin = (N + (1 << WSHIFT) - 1) >> WSHIFT;       // 8 for N = 2^22

    unsigned* gate_cnt = nullptr;
    if (d_ws && ws_size >= MAXGATES * sizeof(unsigned)) {
        gate_cnt = (unsigned*)d_ws;
        hipMemsetAsync(d_ws, 0, MAXGATES * sizeof(unsigned), stream);
    }

    if (F > 0)
        prodseg_main<<<NBLK, BLK, 0, stream>>>(x, ptrs, csr, out, gate_cnt,
                                               E, S, F, nwin);
    if (E0 < E) {
        int nt = (E - E0 + TK - 1) / TK;
        prodseg_tail<<<(nt + 255) / 256, 256, 0, stream>>>(x, ptrs, csr, out, E0, E, S);
    }
}

// Round 7
// 405.711 us; speedup vs baseline: 3.1164x; 3.1164x over previous
//
#include <hip/hip_runtime.h>

// Sorted-segment product: out[i] = prod_{j: csr[j]==i} x[ptrs[j]], empty -> 0.
//
// R7: R5's high-occupancy config (32KB LDS blocks, 4/CU, 85% occ, 3.56 TB/s)
// + TIME-BASED window pacing instead of R6's counter gate (which cost
// ~65us/gate: 1024 same-line atomicAdds + poll storm). Each block anchors
// T0 = wall_clock64() (100MHz constant clock) at entry; before phase p it
// sleeps until T0 + p*WIN_TICKS (+GEN_EXTRA per generation). Zero memory
// traffic, zero contention; slow blocks never wait (self-correcting);
// a sleep budget latches pacing off if the clock model is wrong (worst
// case degrades to R5 drift, never R6 serialization).

#define EPT       16              // edges per thread (pt[16]+g[16] = 32 VGPRs)
#define EPT_SHIFT 4
#define BLK       512             // threads per block (8 waves)
#define MSC       (BLK * EPT)     // 8192 edges per superchunk -> 32KB LDS
#define NBLK      1024            // persistent blocks (~4 per CU)
#define WSHIFT    19              // window = 2^19 floats = 2 MB (nwin = 8)

#define WIN_TICKS   700ULL        // 7 us per window @ 100MHz wall clock
#define GEN_EXTRA   1200ULL       // 12 us product-phase allowance per gen
#define SLEEP_Q     16            // s_sleep(16) ~ 1024 core cycles (~0.43us)
#define MAX_SLEEPS  320           // total pacing budget/block (~140us idle cap)

__global__ __launch_bounds__(BLK, 8) void prodseg_main(
    const float* __restrict__ x,
    const int*   __restrict__ ptrs,
    const int*   __restrict__ csr,
    float*       __restrict__ out,
    int E, int S, int F /* # full superchunks */, int nwin)
{
    __shared__ float gbuf[MSC];   // column-major: edge (t,k) -> gbuf[k*BLK + t]
    __shared__ unsigned long long t0_sh;
    const int t = threadIdx.x;
    if (t == 0) t0_sh = (unsigned long long)wall_clock64();
    __syncthreads();
    const unsigned long long T0 = t0_sh;
    int sleep_budget = MAX_SLEEPS;          // only thread 0's copy matters

    const int ngen = (F + (int)gridDim.x - 1) / (int)gridDim.x;

    for (int gen = 0; gen < ngen; ++gen) {
        int sc = gen * (int)gridDim.x + (int)blockIdx.x;
        if (sc >= F) break;                    // block-uniform exit
        const int sbase = sc * MSC;
        const int gbase = sbase + t * EPT;

        // ---- stage my 16 ptrs into registers (vectorized, aligned) ----
        int pt[EPT];
        {
            const int4* p4 = reinterpret_cast<const int4*>(ptrs + gbase);
            #pragma unroll
            for (int i = 0; i < EPT / 4; ++i) {
                int4 v = p4[i];
                pt[4*i+0] = v.x; pt[4*i+1] = v.y;
                pt[4*i+2] = v.z; pt[4*i+3] = v.w;
            }
        }

        // ---- window-phased gather, wall-clock paced ----
        float g[EPT];
        for (int w = 0; w < nwin; ++w) {
            int phase = gen * nwin + w;
            if (phase > 0) {
                if (t == 0) {
                    unsigned long long tgt = T0
                        + (unsigned long long)phase * WIN_TICKS
                        + (unsigned long long)gen * GEN_EXTRA;
                    while (sleep_budget > 0 &&
                           (unsigned long long)wall_clock64() < tgt) {
                        __builtin_amdgcn_s_sleep(SLEEP_Q);
                        --sleep_budget;
                    }
                }
                __syncthreads();           // release block on schedule
            }
            // 1) predicated loads only — independent, all issue (MLP)
            #pragma unroll
            for (int k = 0; k < EPT; ++k)
                if ((pt[k] >> WSHIFT) == w) g[k] = x[pt[k]];
            // 2) mirror to LDS for cross-thread run walks
            #pragma unroll
            for (int k = 0; k < EPT; ++k)
                if ((pt[k] >> WSHIFT) == w) gbuf[k * BLK + t] = g[k];
            __syncthreads();               // window done; orders gbuf writes
        }

        // ---- product phase (run ownership, exact) ----
        int prev = (gbase == 0) ? -1 : csr[gbase - 1];
        const int4* c4 = reinterpret_cast<const int4*>(csr + gbase);
        int cur = 0; bool own = false; float prod = 1.0f;
        #pragma unroll
        for (int i = 0; i < EPT / 4; ++i) {
            int4 c = c4[i];
            int sv[4] = {c.x, c.y, c.z, c.w};
            #pragma unroll
            for (int j = 0; j < 4; ++j) {
                const int k = 4 * i + j;
                int sg = sv[j];
                if (k == 0) {
                    cur = sg; own = (sg != prev);
                    prod = own ? g[0] : 1.0f;
                    if (own)
                        for (int q = prev + 1; q < cur; ++q) out[q] = 0.0f;
                } else {
                    if (sg == cur) {
                        prod *= g[k];          // harmless if !own (never stored)
                    } else {
                        if (own) out[cur] = prod;
                        for (int q = cur + 1; q < sg; ++q) out[q] = 0.0f;
                        cur = sg; own = true; prod = g[k];
                    }
                }
            }
        }
        // final run: walk forward; in-superchunk values come from LDS
        if (own) {
            int idx = gbase + EPT;
            while (idx < E) {
                if (csr[idx] != cur) break;
                float v;
                int local = idx - sbase;
                if (local < MSC)
                    v = gbuf[(local & (EPT - 1)) * BLK + (local >> EPT_SHIFT)];
                else
                    v = x[ptrs[idx]];
                prod *= v; ++idx;
            }
            out[cur] = prod;
            if (idx == E)
                for (int q = cur + 1; q < S; ++q) out[q] = 0.0f;
        }
        __syncthreads();   // protect gbuf before next generation
    }
}

// Generic tail (E % MSC != 0) — R1-proven logic; not launched for E = 2^24.
#define TK 8
__global__ __launch_bounds__(256) void prodseg_tail(
    const float* __restrict__ x,
    const int*   __restrict__ ptrs,
    const int*   __restrict__ csr,
    float*       __restrict__ out,
    int E0, int E, int S)
{
    int t = blockIdx.x * blockDim.x + threadIdx.x;
    int base = E0 + t * TK;
    if (base >= E) return;
    int prev = (base == 0) ? -1 : csr[base - 1];
    int n = (base + TK <= E) ? TK : (E - base);

    int cur = 0; bool own = false; float prod = 1.0f;
    for (int k = 0; k < n; ++k) {
        int sg = csr[base + k];
        float gv = x[ptrs[base + k]];
        if (k == 0) {
            cur = sg; own = (sg != prev);
            prod = own ? gv : 1.0f;
            if (own) for (int q = prev + 1; q < cur; ++q) out[q] = 0.0f;
        } else if (sg == cur) {
            prod *= gv;
        } else {
            if (own) out[cur] = prod;
            for (int q = cur + 1; q < sg; ++q) out[q] = 0.0f;
            cur = sg; own = true; prod = gv;
        }
    }
    if (own) {
        int idx = base + n;
        while (idx < E && csr[idx] == cur) { prod *= x[ptrs[idx]]; ++idx; }
        out[cur] = prod;
        if (idx == E) for (int q = cur + 1; q < S; ++q) out[q] = 0.0f;
    }
}

extern "C" void kernel_launch(void* const* d_in, const int* in_sizes, int n_in,
                              void* d_out, int out_size, void* d_ws, size_t ws_size,
                              hipStream_t stream) {
    const float* x    = (const float*)d_in[0];
    const int*   ptrs = (const int*)d_in[1];
    const int*   csr  = (const int*)d_in[2];
    float*       out  = (float*)d_out;
    int N = in_sizes[0];
    int E = in_sizes[1];
    int S = out_size;

    int F  = E / MSC;                                   // full superchunks
    int E0 = F * MSC;
    int nwin = (N + (1 << WSHIFT) - 1) >> WSHIFT;       // 8 for N = 2^22

    if (F > 0)
        prodseg_main<<<NBLK, BLK, 0, stream>>>(x, ptrs, csr, out, E, S, F, nwin);
    if (E0 < E) {
        int nt = (E - E0 + TK - 1) / TK;
        prodseg_tail<<<(nt + 255) / 256, 256, 0, stream>>>(x, ptrs, csr, out, E0, E, S);
    }
}

// Round 8
// 338.367 us; speedup vs baseline: 3.7366x; 1.1990x over previous
//
#include <hip/hip_runtime.h>

// Sorted-segment product: out[i] = prod_{j: csr[j]==i} x[ptrs[j]], empty -> 0.
//
// R8: guaranteed-residency window phasing. Drift diagnosis: R4/R5's extra
// x-sweeps came from blocks that weren't co-resident at launch (85%/46% occ)
// starting their window sweep late. Fix: shrink LDS so residency is capped
// ONLY by the 32-wave/CU limit. The 32KB gbuf mirror (values of all chunk
// edges, for cross-chunk run walks) is replaced by 6KB of per-thread run
// summaries {head_seg, head_prod, all_same}: a cross-boundary walk consumes
// whole chunks in O(1) lookups (runs <= ~48 edges => <=3 steps).
// Config: BLK=512, EPT=16, MSC=8192, NBLK=1024 (4 blocks/CU, 32 waves/CU,
// ALL co-resident), ngen=2, 1MB windows (nwin=16).

#define EPT       16              // edges per thread (pt[16]+g[16] = 32 VGPRs)
#define BLK       512             // threads per block (8 waves)
#define MSC       (BLK * EPT)     // 8192 edges per superchunk
#define NBLK      1024            // persistent blocks (4 per CU, all resident)
#define WSHIFT    18              // window = 2^18 floats = 1 MB (nwin = 16)

__global__ __launch_bounds__(BLK, 8) void prodseg_main(
    const float* __restrict__ x,
    const int*   __restrict__ ptrs,
    const int*   __restrict__ csr,
    float*       __restrict__ out,
    int E, int S, int F /* # full superchunks */, int nwin)
{
    __shared__ int   e_seg[BLK];    // head segment id of thread's chunk
    __shared__ float e_prod[BLK];   // product of the chunk's LEADING run
    __shared__ int   e_all[BLK];    // 1 if whole chunk is one segment
    const int t = threadIdx.x;
    const int ngen = (F + (int)gridDim.x - 1) / (int)gridDim.x;

    for (int gen = 0; gen < ngen; ++gen) {
        int sc = gen * (int)gridDim.x + (int)blockIdx.x;
        if (sc >= F) break;                    // block-uniform exit
        const int sbase = sc * MSC;
        const int gbase = sbase + t * EPT;

        // ---- stage my 16 ptrs into registers (vectorized, aligned) ----
        int pt[EPT];
        {
            const int4* p4 = reinterpret_cast<const int4*>(ptrs + gbase);
            #pragma unroll
            for (int i = 0; i < EPT / 4; ++i) {
                int4 v = p4[i];
                pt[4*i+0] = v.x; pt[4*i+1] = v.y;
                pt[4*i+2] = v.z; pt[4*i+3] = v.w;
            }
        }

        // ---- window-phased gather (per-window block barrier paces waves;
        //      __syncthreads drains vmcnt, so window w's loads land before
        //      any wave of this block starts window w+1) ----
        float g[EPT];
        for (int w = 0; w < nwin; ++w) {
            #pragma unroll
            for (int k = 0; k < EPT; ++k)
                if ((pt[k] >> WSHIFT) == w) g[k] = x[pt[k]];
            __syncthreads();
        }

        // ---- phase A: interior runs + per-chunk head summary ----
        int prev = (gbase == 0) ? -1 : csr[gbase - 1];
        const int4* c4 = reinterpret_cast<const int4*>(csr + gbase);
        int cur = 0; bool own = false; float prod = 1.0f;
        int hseg = 0; float hprod = 1.0f; bool in_head = true;
        #pragma unroll
        for (int i = 0; i < EPT / 4; ++i) {
            int4 c = c4[i];
            int sv[4] = {c.x, c.y, c.z, c.w};
            #pragma unroll
            for (int j = 0; j < 4; ++j) {
                const int k = 4 * i + j;
                int sg = sv[j];
                if (k == 0) {
                    hseg = sg; hprod = g[0];
                    cur = sg; own = (sg != prev);
                    prod = g[0];
                    if (own)
                        for (int q = prev + 1; q < cur; ++q) out[q] = 0.0f;
                } else {
                    if (sg == cur) {
                        prod *= g[k];
                        if (in_head) hprod *= g[k];
                    } else {
                        in_head = false;
                        if (own) out[cur] = prod;   // run ended inside chunk
                        for (int q = cur + 1; q < sg; ++q) out[q] = 0.0f;
                        cur = sg; own = true; prod = g[k];
                    }
                }
            }
        }
        e_seg[t]  = hseg;
        e_prod[t] = hprod;
        e_all[t]  = in_head ? 1 : 0;
        __syncthreads();

        // ---- phase B: final-run walk via chunk summaries ----
        if (own) {
            int u = t + 1;
            bool hit_end = false;
            while (true) {
                if (u < BLK) {
                    if (e_seg[u] == cur) {
                        prod *= e_prod[u];
                        if (e_all[u]) { ++u; continue; }
                    }
                    break;   // run ends inside chunk u (or before it)
                } else {
                    // crossed superchunk boundary: rare global walk
                    int idx = sbase + MSC;
                    while (idx < E && csr[idx] == cur) {
                        prod *= x[ptrs[idx]];
                        ++idx;
                    }
                    if (idx == E) hit_end = true;
                    break;
                }
            }
            out[cur] = prod;
            if (hit_end)
                for (int q = cur + 1; q < S; ++q) out[q] = 0.0f;
        }
        __syncthreads();   // protect e_* before next generation
    }
}

// Generic tail (E % MSC != 0) — R1-proven logic; not launched for E = 2^24.
#define TK 8
__global__ __launch_bounds__(256) void prodseg_tail(
    const float* __restrict__ x,
    const int*   __restrict__ ptrs,
    const int*   __restrict__ csr,
    float*       __restrict__ out,
    int E0, int E, int S)
{
    int t = blockIdx.x * blockDim.x + threadIdx.x;
    int base = E0 + t * TK;
    if (base >= E) return;
    int prev = (base == 0) ? -1 : csr[base - 1];
    int n = (base + TK <= E) ? TK : (E - base);

    int cur = 0; bool own = false; float prod = 1.0f;
    for (int k = 0; k < n; ++k) {
        int sg = csr[base + k];
        float gv = x[ptrs[base + k]];
        if (k == 0) {
            cur = sg; own = (sg != prev);
            prod = own ? gv : 1.0f;
            if (own) for (int q = prev + 1; q < cur; ++q) out[q] = 0.0f;
        } else if (sg == cur) {
            prod *= gv;
        } else {
            if (own) out[cur] = prod;
            for (int q = cur + 1; q < sg; ++q) out[q] = 0.0f;
            cur = sg; own = true; prod = gv;
        }
    }
    if (own) {
        int idx = base + n;
        while (idx < E && csr[idx] == cur) { prod *= x[ptrs[idx]]; ++idx; }
        out[cur] = prod;
        if (idx == E) for (int q = cur + 1; q < S; ++q) out[q] = 0.0f;
    }
}

extern "C" void kernel_launch(void* const* d_in, const int* in_sizes, int n_in,
                              void* d_out, int out_size, void* d_ws, size_t ws_size,
                              hipStream_t stream) {
    const float* x    = (const float*)d_in[0];
    const int*   ptrs = (const int*)d_in[1];
    const int*   csr  = (const int*)d_in[2];
    float*       out  = (float*)d_out;
    int N = in_sizes[0];
    int E = in_sizes[1];
    int S = out_size;

    int F  = E / MSC;                                   // full superchunks
    int E0 = F * MSC;
    int nwin = (N + (1 << WSHIFT) - 1) >> WSHIFT;       // 16 for N = 2^22

    if (F > 0)
        prodseg_main<<<NBLK, BLK, 0, stream>>>(x, ptrs, csr, out, E, S, F, nwin);
    if (E0 < E) {
        int nt = (E - E0 + TK - 1) / TK;
        prodseg_tail<<<(nt + 255) / 256, 256, 0, stream>>>(x, ptrs, csr, out, E0, E, S);
    }
}

// Round 9
// 313.886 us; speedup vs baseline: 4.0280x; 1.0780x over previous
//
#include <hip/hip_runtime.h>

// Sorted-segment product: out[i] = prod_{j: csr[j]==i} x[ptrs[j]], empty -> 0.
//
// R9: single-generation sweep. R8 (summaries, 6KB LDS) still paid 2
// structural x-sweeps (2 generations) + drift. Now one generation covers
// all of E: BLK=1024, EPT=16, MSC=16384, NBLK=1024=F, ngen=1 -> each XCD
// fills x ONCE (128MB floor), 16 window phases total, product phase runs
// exactly once at the end. LDS = 12KB summaries -> 2 blocks/CU x 16 waves
// = 32 waves/CU co-resident. Cross-chunk run walks use per-thread
// summaries {head_seg, head_prod, all_same} (O(1) per chunk).

#define EPT       16              // edges per thread (pt[16]+g[16] = 32 VGPRs)
#define BLK       1024            // threads per block (16 waves)
#define MSC       (BLK * EPT)     // 16384 edges per superchunk
#define NBLK      1024            // = F: one superchunk per block, 1 gen
#define WSHIFT    18              // window = 2^18 floats = 1 MB (nwin = 16)

__global__ __launch_bounds__(BLK, 8) void prodseg_main(
    const float* __restrict__ x,
    const int*   __restrict__ ptrs,
    const int*   __restrict__ csr,
    float*       __restrict__ out,
    int E, int S, int F /* # full superchunks */, int nwin)
{
    __shared__ int   e_seg[BLK];    // head segment id of thread's chunk
    __shared__ float e_prod[BLK];   // product of the chunk's LEADING run
    __shared__ int   e_all[BLK];    // 1 if whole chunk is one segment
    const int t = threadIdx.x;
    const int ngen = (F + (int)gridDim.x - 1) / (int)gridDim.x;

    for (int gen = 0; gen < ngen; ++gen) {
        int sc = gen * (int)gridDim.x + (int)blockIdx.x;
        if (sc >= F) break;                    // block-uniform exit
        const int sbase = sc * MSC;
        const int gbase = sbase + t * EPT;

        // ---- stage my 16 ptrs into registers (vectorized, aligned) ----
        int pt[EPT];
        {
            const int4* p4 = reinterpret_cast<const int4*>(ptrs + gbase);
            #pragma unroll
            for (int i = 0; i < EPT / 4; ++i) {
                int4 v = p4[i];
                pt[4*i+0] = v.x; pt[4*i+1] = v.y;
                pt[4*i+2] = v.z; pt[4*i+3] = v.w;
            }
        }

        // ---- window-phased gather (per-window block barrier paces the
        //      block's 16 waves; barrier drains vmcnt so window w's loads
        //      land before any wave starts window w+1) ----
        float g[EPT];
        for (int w = 0; w < nwin; ++w) {
            #pragma unroll
            for (int k = 0; k < EPT; ++k)
                if ((pt[k] >> WSHIFT) == w) g[k] = x[pt[k]];
            __syncthreads();
        }

        // ---- phase A: interior runs + per-chunk head summary ----
        int prev = (gbase == 0) ? -1 : csr[gbase - 1];
        const int4* c4 = reinterpret_cast<const int4*>(csr + gbase);
        int cur = 0; bool own = false; float prod = 1.0f;
        int hseg = 0; float hprod = 1.0f; bool in_head = true;
        #pragma unroll
        for (int i = 0; i < EPT / 4; ++i) {
            int4 c = c4[i];
            int sv[4] = {c.x, c.y, c.z, c.w};
            #pragma unroll
            for (int j = 0; j < 4; ++j) {
                const int k = 4 * i + j;
                int sg = sv[j];
                if (k == 0) {
                    hseg = sg; hprod = g[0];
                    cur = sg; own = (sg != prev);
                    prod = g[0];
                    if (own)
                        for (int q = prev + 1; q < cur; ++q) out[q] = 0.0f;
                } else {
                    if (sg == cur) {
                        prod *= g[k];
                        if (in_head) hprod *= g[k];
                    } else {
                        in_head = false;
                        if (own) out[cur] = prod;   // run ended inside chunk
                        for (int q = cur + 1; q < sg; ++q) out[q] = 0.0f;
                        cur = sg; own = true; prod = g[k];
                    }
                }
            }
        }
        e_seg[t]  = hseg;
        e_prod[t] = hprod;
        e_all[t]  = in_head ? 1 : 0;
        __syncthreads();

        // ---- phase B: final-run walk via chunk summaries ----
        if (own) {
            int u = t + 1;
            bool hit_end = false;
            while (true) {
                if (u < BLK) {
                    if (e_seg[u] == cur) {
                        prod *= e_prod[u];
                        if (e_all[u]) { ++u; continue; }
                    }
                    break;   // run ends inside chunk u (or before it)
                } else {
                    // crossed superchunk boundary: rare global walk
                    int idx = sbase + MSC;
                    while (idx < E && csr[idx] == cur) {
                        prod *= x[ptrs[idx]];
                        ++idx;
                    }
                    if (idx == E) hit_end = true;
                    break;
                }
            }
            out[cur] = prod;
            if (hit_end)
                for (int q = cur + 1; q < S; ++q) out[q] = 0.0f;
        }
        __syncthreads();   // protect e_* before next generation
    }
}

// Generic tail (E % MSC != 0) — R1-proven logic; not launched for E = 2^24.
#define TK 8
__global__ __launch_bounds__(256) void prodseg_tail(
    const float* __restrict__ x,
    const int*   __restrict__ ptrs,
    const int*   __restrict__ csr,
    float*       __restrict__ out,
    int E0, int E, int S)
{
    int t = blockIdx.x * blockDim.x + threadIdx.x;
    int base = E0 + t * TK;
    if (base >= E) return;
    int prev = (base == 0) ? -1 : csr[base - 1];
    int n = (base + TK <= E) ? TK : (E - base);

    int cur = 0; bool own = false; float prod = 1.0f;
    for (int k = 0; k < n; ++k) {
        int sg = csr[base + k];
        float gv = x[ptrs[base + k]];
        if (k == 0) {
            cur = sg; own = (sg != prev);
            prod = own ? gv : 1.0f;
            if (own) for (int q = prev + 1; q < cur; ++q) out[q] = 0.0f;
        } else if (sg == cur) {
            prod *= gv;
        } else {
            if (own) out[cur] = prod;
            for (int q = cur + 1; q < sg; ++q) out[q] = 0.0f;
            cur = sg; own = true; prod = gv;
        }
    }
    if (own) {
        int idx = base + n;
        while (idx < E && csr[idx] == cur) { prod *= x[ptrs[idx]]; ++idx; }
        out[cur] = prod;
        if (idx == E) for (int q = cur + 1; q < S; ++q) out[q] = 0.0f;
    }
}

extern "C" void kernel_launch(void* const* d_in, const int* in_sizes, int n_in,
                              void* d_out, int out_size, void* d_ws, size_t ws_size,
                              hipStream_t stream) {
    const float* x    = (const float*)d_in[0];
    const int*   ptrs = (const int*)d_in[1];
    const int*   csr  = (const int*)d_in[2];
    float*       out  = (float*)d_out;
    int N = in_sizes[0];
    int E = in_sizes[1];
    int S = out_size;

    int F  = E / MSC;                                   // 1024 superchunks
    int E0 = F * MSC;
    int nwin = (N + (1 << WSHIFT) - 1) >> WSHIFT;       // 16 for N = 2^22

    if (F > 0)
        prodseg_main<<<NBLK, BLK, 0, stream>>>(x, ptrs, csr, out, E, S, F, nwin);
    if (E0 < E) {
        int nt = (E - E0 + TK - 1) / TK;
        prodseg_tail<<<(nt + 255) / 256, 256, 0, stream>>>(x, ptrs, csr, out, E0, E, S);
    }
}